// Round 1
// baseline (389.808 us; speedup 1.0000x reference)
//
#include <hip/hip_runtime.h>
#include <hip/hip_bf16.h>

#define NB 2
#define NT 2048
#define NC 1024
#define NH 16
#define HD 64

typedef __attribute__((ext_vector_type(8))) short short8;
typedef __attribute__((ext_vector_type(4))) short short4_;
typedef __attribute__((ext_vector_type(4))) float f32x4;
typedef unsigned short u16;

__device__ __forceinline__ u16 f2bf(float x) {
  union { float f; unsigned u; } c; c.f = x;
  unsigned r = (c.u + 0x7fffu + ((c.u >> 16) & 1u)) >> 16;
  return (u16)r;
}

// ---------------- prep kernels ----------------

__global__ void cvt_x_kernel(const float* __restrict__ in, u16* __restrict__ out, int n) {
  int i = (blockIdx.x * blockDim.x + threadIdx.x) * 4;
  if (i < n) {
    float4 v = *(const float4*)(in + i);
    short4_ o;
    o.x = (short)f2bf(v.x); o.y = (short)f2bf(v.y);
    o.z = (short)f2bf(v.z); o.w = (short)f2bf(v.w);
    *(short4_*)(out + i) = o;
  }
}

// in [K][N] f32 -> out [N][K] bf16
__global__ void transpose_w_kernel(const float* __restrict__ in, u16* __restrict__ out,
                                   int K, int N) {
  __shared__ float tile[32][33];
  int k0 = blockIdx.x * 32, n0 = blockIdx.y * 32;
  int tx = threadIdx.x, ty = threadIdx.y;  // (32,8)
  for (int r = ty; r < 32; r += 8)
    tile[r][tx] = in[(size_t)(k0 + r) * N + n0 + tx];
  __syncthreads();
  for (int r = ty; r < 32; r += 8)
    out[(size_t)(n0 + r) * K + k0 + tx] = f2bf(tile[tx][r]);
}

// ---------------- GEMM (m97 structure): C = A[M,K] @ Bt[N,K]^T + bias ----------------
// EPI 0: scatter to K/Q ([b,h,t,d]) and Vt ([b,h,d,t]) bf16.  EPI 1: f32 out + bias.

template <int EPI>
__global__ __launch_bounds__(256, 2) void gemm_nt(
    const u16* __restrict__ A, const u16* __restrict__ Bt,
    const float* __restrict__ bias,
    u16* __restrict__ o_k, u16* __restrict__ o_q, u16* __restrict__ o_vt,
    float* __restrict__ o_f, int M, int N, int K) {
  __shared__ u16 As[128 * 32];
  __shared__ u16 Bs[128 * 32];
  int tid = threadIdx.x;
  int w = tid >> 6, l = tid & 63;
  int wr = w >> 1, wc = w & 1;
  int lr = l & 15, lk = l >> 4;
  int bm = blockIdx.x, bn = blockIdx.y;

  const u16* Ab = A + (size_t)bm * 128 * K;
  const u16* Bb = Bt + (size_t)bn * 128 * K;

  f32x4 acc[4][4];
#pragma unroll
  for (int m = 0; m < 4; m++)
#pragma unroll
    for (int n = 0; n < 4; n++) acc[m][n] = (f32x4){0.f, 0.f, 0.f, 0.f};

  for (int ks = 0; ks < K; ks += 32) {
    __syncthreads();
#pragma unroll
    for (int it = 0; it < 2; ++it) {
      int chunk = it * 256 + tid;     // 512 chunks of 16B per tile
      int r = chunk >> 2, kg = chunk & 3;
      const u16* ga = Ab + (size_t)r * K + ks + kg * 8;
      const u16* gb = Bb + (size_t)r * K + ks + kg * 8;
      u16* la = As + (size_t)(it * 256 + w * 64) * 8;  // wave-uniform base
      u16* lb = Bs + (size_t)(it * 256 + w * 64) * 8;
      __builtin_amdgcn_global_load_lds((const __attribute__((address_space(1))) void*)ga,
                                       (__attribute__((address_space(3))) void*)la, 16, 0, 0);
      __builtin_amdgcn_global_load_lds((const __attribute__((address_space(1))) void*)gb,
                                       (__attribute__((address_space(3))) void*)lb, 16, 0, 0);
    }
    __syncthreads();
    short8 a[4], b[4];
#pragma unroll
    for (int m = 0; m < 4; m++)
      a[m] = *(const short8*)(As + (size_t)(wr * 64 + m * 16 + lr) * 32 + lk * 8);
#pragma unroll
    for (int n = 0; n < 4; n++)
      b[n] = *(const short8*)(Bs + (size_t)(wc * 64 + n * 16 + lr) * 32 + lk * 8);
#pragma unroll
    for (int m = 0; m < 4; m++)
#pragma unroll
      for (int n = 0; n < 4; n++)
        acc[m][n] = __builtin_amdgcn_mfma_f32_16x16x32_bf16(a[m], b[n], acc[m][n], 0, 0, 0);
  }

#pragma unroll
  for (int m = 0; m < 4; m++) {
    int gm0 = bm * 128 + wr * 64 + m * 16 + lk * 4;
#pragma unroll
    for (int n = 0; n < 4; n++) {
      int gn = bn * 128 + wc * 64 + n * 16 + lr;
      float bv = bias[gn];
#pragma unroll
      for (int j = 0; j < 4; j++) {
        float v = acc[m][n][j] + bv;
        int row = gm0 + j;
        if constexpr (EPI == 0) {
          int b_ = row >> 11, t_ = row & (NT - 1);
          int head = gn / 192;
          int rem = gn - head * 192;
          int typ = rem >> 6, d = rem & 63;
          if (typ == 0)
            o_k[(((size_t)(b_ * NH + head)) * NT + t_) * HD + d] = f2bf(v);
          else if (typ == 1)
            o_q[(((size_t)(b_ * NH + head)) * NT + t_) * HD + d] = f2bf(v);
          else
            o_vt[(((size_t)(b_ * NH + head)) * HD + d) * NT + t_] = f2bf(v);
        } else {
          o_f[(size_t)row * N + gn] = v;
        }
      }
    }
  }
}

// ---------------- flash attention (causal), S^T = K @ Q^T trick ----------------
// grid (T/64, B*H), 256 threads = 4 independent waves; wave w owns 16 q-rows.

__global__ __launch_bounds__(256, 2) void attn_kernel(
    const u16* __restrict__ Kb, const u16* __restrict__ Qb,
    const u16* __restrict__ Vt, u16* __restrict__ Y) {
  int tid = threadIdx.x;
  int w = tid >> 6, l = tid & 63;
  int lr = l & 15, lg = l >> 4;
  int qb = blockIdx.x;
  int bh = blockIdx.y;
  int q0 = qb * 64 + w * 16;

  const u16* Kp = Kb + (size_t)bh * NT * HD;
  const u16* Qp = Qb + (size_t)bh * NT * HD;
  const u16* Vp = Vt + (size_t)bh * HD * NT;

  __shared__ u16 Pl[4][16 * 64];
  u16* Pw = &Pl[w][0];

  // Q fragments (B-operand of S^T): lane holds Q[q0+lr][c*32+lg*8 .. +8]
  short8 qf[2];
#pragma unroll
  for (int c = 0; c < 2; c++)
    qf[c] = *(const short8*)(Qp + (size_t)(q0 + lr) * HD + c * 32 + lg * 8);

  f32x4 accO[4];
#pragma unroll
  for (int n = 0; n < 4; n++) accO[n] = (f32x4){0.f, 0.f, 0.f, 0.f};
  float mrow = -1e30f, lsum = 0.f;
  int qg = q0 + lr;

  for (int kt = 0; kt <= qb; ++kt) {
    int mtmax = (kt == qb) ? (w + 1) : 4;  // wave-uniform
    float s[4][4];
#pragma unroll
    for (int mt = 0; mt < 4; ++mt) {
      if (mt < mtmax) {
        f32x4 a = (f32x4){0.f, 0.f, 0.f, 0.f};
#pragma unroll
        for (int c = 0; c < 2; c++) {
          short8 kf = *(const short8*)(Kp + (size_t)(kt * 64 + mt * 16 + lr) * HD + c * 32 + lg * 8);
          a = __builtin_amdgcn_mfma_f32_16x16x32_bf16(kf, qf[c], a, 0, 0, 0);
        }
#pragma unroll
        for (int j = 0; j < 4; j++) {
          int kvg = kt * 64 + mt * 16 + lg * 4 + j;
          float v = a[j] * 0.125f;  // 1/sqrt(64)
          s[mt][j] = (kvg <= qg) ? v : -1e30f;
        }
      } else {
#pragma unroll
        for (int j = 0; j < 4; j++) s[mt][j] = -1e30f;
      }
    }
    // online softmax along kv (per column q = lane's lr)
    float mt_ = -1e30f;
#pragma unroll
    for (int mt = 0; mt < 4; mt++)
#pragma unroll
      for (int j = 0; j < 4; j++) mt_ = fmaxf(mt_, s[mt][j]);
    mt_ = fmaxf(mt_, __shfl_xor(mt_, 16));
    mt_ = fmaxf(mt_, __shfl_xor(mt_, 32));
    float mnew = fmaxf(mrow, mt_);
    float alpha = __expf(mrow - mnew);
    float ps = 0.f;
#pragma unroll
    for (int mt = 0; mt < 4; mt++)
#pragma unroll
      for (int j = 0; j < 4; j++) {
        float p = __expf(s[mt][j] - mnew);
        s[mt][j] = p;
        ps += p;
      }
    ps += __shfl_xor(ps, 16);
    ps += __shfl_xor(ps, 32);
    lsum = lsum * alpha + ps;
    mrow = mnew;

    __syncthreads();  // prev iter's P reads done before overwrite
    // store P[q=lr][kv] bf16, XOR-swizzled
#pragma unroll
    for (int mt = 0; mt < 4; mt++)
#pragma unroll
      for (int j = 0; j < 4; j++) {
        int kv = mt * 16 + lg * 4 + j;
        int bo = (lr * 128 + kv * 2) ^ ((lr & 7) << 4);
        *(u16*)((char*)Pw + bo) = f2bf(s[mt][j]);
      }
    // rescale O by alpha (O rows are q = lg*4+j)
    float aj[4];
#pragma unroll
    for (int j = 0; j < 4; j++) aj[j] = __shfl(alpha, lg * 4 + j);
#pragma unroll
    for (int n = 0; n < 4; n++) {
      f32x4 t = accO[n];
#pragma unroll
      for (int j = 0; j < 4; j++) t[j] *= aj[j];
      accO[n] = t;
    }
    __syncthreads();  // P writes visible
    // O += P @ V   (B-operand direct from global V^T, contiguous)
#pragma unroll
    for (int c = 0; c < 2; c++) {
      int bo = (lr * 128 + c * 64 + lg * 16) ^ ((lr & 7) << 4);
      short8 pa = *(const short8*)((const char*)Pw + bo);
#pragma unroll
      for (int n = 0; n < 4; n++) {
        short8 vf = *(const short8*)(Vp + (size_t)(n * 16 + lr) * NT + kt * 64 + c * 32 + lg * 8);
        accO[n] = __builtin_amdgcn_mfma_f32_16x16x32_bf16(pa, vf, accO[n], 0, 0, 0);
      }
    }
  }

  float rl[4];
#pragma unroll
  for (int j = 0; j < 4; j++) rl[j] = 1.0f / __shfl(lsum, lg * 4 + j);
  int b_ = bh >> 4, h_ = bh & 15;
#pragma unroll
  for (int n = 0; n < 4; n++)
#pragma unroll
    for (int j = 0; j < 4; j++) {
      int q = q0 + lg * 4 + j;
      Y[((size_t)(b_ * NT + q)) * NC + h_ * HD + n * 16 + lr] = f2bf(accO[n][j] * rl[j]);
    }
}

// ---------------- launch ----------------

extern "C" void kernel_launch(void* const* d_in, const int* in_sizes, int n_in,
                              void* d_out, int out_size, void* d_ws, size_t ws_size,
                              hipStream_t stream) {
  const float* x      = (const float*)d_in[0];
  // d_in[1] = att_mask (always tril(ones) -> causal hardcoded)
  const float* w_kqv  = (const float*)d_in[2];
  const float* b_kqv  = (const float*)d_in[3];
  const float* w_proj = (const float*)d_in[4];
  const float* b_proj = (const float*)d_in[5];
  float* out = (float*)d_out;

  const size_t M = (size_t)NB * NT;  // 4096
  u16* xb     = (u16*)d_ws;                        // 4M elems
  u16* wkqvT  = xb + M * NC;                       // 3M
  u16* wprojT = wkqvT + (size_t)3 * NC * NC;       // 1M
  u16* Kb     = wprojT + (size_t)NC * NC;          // 4M
  u16* Qb     = Kb + M * NC;
  u16* Vt     = Qb + M * NC;
  u16* Yb     = Vt + M * NC;                       // total 48 MB

  int nx = (int)(M * NC);
  cvt_x_kernel<<<nx / (256 * 4), 256, 0, stream>>>(x, xb, nx);
  dim3 tb(32, 8);
  transpose_w_kernel<<<dim3(NC / 32, 3 * NC / 32), tb, 0, stream>>>(w_kqv, wkqvT, NC, 3 * NC);
  transpose_w_kernel<<<dim3(NC / 32, NC / 32), tb, 0, stream>>>(w_proj, wprojT, NC, NC);

  gemm_nt<0><<<dim3(32, 24), 256, 0, stream>>>(xb, wkqvT, b_kqv, Kb, Qb, Vt, nullptr,
                                               (int)M, 3 * NC, NC);
  attn_kernel<<<dim3(NT / 64, NB * NH), 256, 0, stream>>>(Kb, Qb, Vt, Yb);
  gemm_nt<1><<<dim3(32, 8), 256, 0, stream>>>(Yb, wprojT, b_proj, nullptr, nullptr, nullptr,
                                              out, (int)M, NC, NC);
}